// Round 6
// baseline (363.914 us; speedup 1.0000x reference)
//
#include <hip/hip_runtime.h>

#define BB    8
#define CC    64
#define NN    2048
#define GG    2048
#define MFREQ 4032

typedef __attribute__((ext_vector_type(4))) float f32x4;
typedef __attribute__((ext_vector_type(8))) short bf16x8;

static __device__ __forceinline__ unsigned short f2bf(float f) {
    union { float f; unsigned u; } v; v.f = f;
    unsigned r = v.u + 0x7fff + ((v.u >> 16) & 1);   // RNE
    return (unsigned short)(r >> 16);
}

static __device__ __forceinline__ unsigned int pk2(float lo, float hi) {
    return (unsigned int)f2bf(lo) | ((unsigned int)f2bf(hi) << 16);
}

static __device__ __forceinline__ uint4 pack_unit(float4 a, float4 b, int mode) {
    uint4 o;
    if (mode == 3) { o.x = o.y = o.z = o.w = 0u; return o; }
    if (mode == 2) {
        o.x = pk2(a.w, a.z); o.y = pk2(a.y, a.x);
        o.z = pk2(b.w, b.z); o.w = pk2(b.y, b.x);
    } else if (mode == 1) {
        o.x = pk2(-a.x, -a.y); o.y = pk2(-a.z, -a.w);
        o.z = pk2(-b.x, -b.y); o.w = pk2(-b.z, -b.w);
    } else {
        o.x = pk2(a.x, a.y); o.y = pk2(a.z, a.w);
        o.z = pk2(b.x, b.y); o.w = pk2(b.z, b.w);
    }
    return o;
}

#define ASYNC_COPY16(gp, lp)                                                        \
    __builtin_amdgcn_global_load_lds(                                               \
        (const __attribute__((address_space(1))) unsigned int*)(gp),                \
        (__attribute__((address_space(3))) unsigned int*)(lp), 16, 0, 0)

// ---------------------------------------------------------------------------
// Merged prep v4: Mi and Xb are GONE (folded into GEMM staging).
//  blocks [0, 2048)      : Af pack [4096 x 2048] (2 units/thread)
//  blocks [2048, 10240)  : Wt transpose (32x32 LDS tiles)
//  blocks [10240, 12288) : phi
__global__ __launch_bounds__(256) void prep_all(const float* __restrict__ vf_re,
                                                const float* __restrict__ vf_im,
                                                const float* __restrict__ w1_re,
                                                const float* __restrict__ w1_im,
                                                const float* __restrict__ w2_re,
                                                const float* __restrict__ w2_im,
                                                const float* __restrict__ m1_re,
                                                const float* __restrict__ m1_im,
                                                const float* __restrict__ m2_re,
                                                const float* __restrict__ m2_im,
                                                const float* __restrict__ emb,
                                                unsigned short* __restrict__ af,
                                                unsigned int* __restrict__ wt,
                                                float* __restrict__ phi_re,
                                                float* __restrict__ phi_im) {
    __shared__ float sre[32][33];
    __shared__ float sim[32][33];
    __shared__ float sr4[4], si4[4];
    int blk = blockIdx.x;
    int t = threadIdx.x;

    if (blk < 2048) {
        // ---------------- Af pack: row-permuted bf16 cast of Vf -------------
        #pragma unroll
        for (int u = 0; u < 2; ++u) {
            int gi = blk * 512 + u * 256 + t;
            int m = gi >> 8;                 // 256 groups per 2048-wide row
            int q8 = (gi & 255) * 8;
            int g = m & 2047;
            int f = (g >> 5) * 63 + (g & 31);
            const float* src = (m < 2048 ? vf_re : vf_im) + (size_t)f * 2048 + q8;
            float4 a = *(const float4*)src;
            float4 b = *(const float4*)(src + 4);
            *(uint4*)(af + (size_t)m * 2048 + q8) = pack_unit(a, b, 0);
        }
    } else if (blk < 10240) {
        // ---------------- weight transpose, 32x32 tiles ---------------------
        int bi = blk - 2048;             // [0, 8192)
        int wsel = bi >> 12;             // 4096 tiles per w
        int bj = bi & 4095;
        int io0 = (bj >> 5) * 32;        // 128 io-tiles
        int xy0 = (bj & 31) * 32;        // 32 xy-tiles
        const float* wre = wsel ? w2_re : w1_re;
        const float* wim = wsel ? w2_im : w1_im;
        int r = t >> 3, c4 = (t & 7) * 4;
        float4 a = *(const float4*)(wre + (size_t)(io0 + r) * 1024 + xy0 + c4);
        float4 b = *(const float4*)(wim + (size_t)(io0 + r) * 1024 + xy0 + c4);
        sre[r][c4 + 0] = a.x; sre[r][c4 + 1] = a.y; sre[r][c4 + 2] = a.z; sre[r][c4 + 3] = a.w;
        sim[r][c4 + 0] = b.x; sim[r][c4 + 1] = b.y; sim[r][c4 + 2] = b.z; sim[r][c4 + 3] = b.w;
        __syncthreads();
        int gr = t >> 3, ic4 = (t & 7) * 4;
        uint4 o;
        o.x = (unsigned int)f2bf(sre[ic4 + 0][gr]) | ((unsigned int)f2bf(sim[ic4 + 0][gr]) << 16);
        o.y = (unsigned int)f2bf(sre[ic4 + 1][gr]) | ((unsigned int)f2bf(sim[ic4 + 1][gr]) << 16);
        o.z = (unsigned int)f2bf(sre[ic4 + 2][gr]) | ((unsigned int)f2bf(sim[ic4 + 2][gr]) << 16);
        o.w = (unsigned int)f2bf(sre[ic4 + 3][gr]) | ((unsigned int)f2bf(sim[ic4 + 3][gr]) << 16);
        int g = xy0 + gr + wsel * 1024;
        *(uint4*)(wt + (size_t)g * 4096 + io0 + ic4) = o;
    } else {
        // ---------------- phi ----------------------------------------------
        int g = blk - 10240, e = t;
        int xy = g & 1023;
        const float* mr = (g < 1024 ? m1_re : m2_re) + xy * 256;
        const float* mp = (g < 1024 ? m1_im : m2_im) + xy * 256;
        float vr = mr[e], vi = mp[e];
        for (int bb = 0; bb < 8; ++bb) {
            float em = emb[bb * 256 + e];
            float pr = vr * em, pi = vi * em;
            for (int s = 32; s > 0; s >>= 1) { pr += __shfl_down(pr, s); pi += __shfl_down(pi, s); }
            int wid = e >> 6;
            if ((e & 63) == 0) { sr4[wid] = pr; si4[wid] = pi; }
            __syncthreads();
            if (e == 0) {
                phi_re[bb * 2048 + g] = sr4[0] + sr4[1] + sr4[2] + sr4[3];
                phi_im[bb * 2048 + g] = si4[0] + si4[1] + si4[2] + si4[3];
            }
            __syncthreads();
        }
    }
}

// ---------------------------------------------------------------------------
// Split-K MFMA GEMM, tile TM x TM, serial R3 schedule (proven).
// A is always bf16, staged via global_load_lds.
// B staging by BMODE:
//   1: f32 direct (row-major [N][K] floats, e.g. x) -> cvt bf16 in regs
//   2: Hermitian decode of Vi (vi_re/vi_im [N][MFREQ]) -> cvt bf16 in regs
// ilv=1 (forward): store element (rr,cc) at ((rr&2047)*1024 + cc*2 + (rr>>11)).
template<int TM, int BMODE>
__global__ __launch_bounds__(256, 2) void gemm_sk(const unsigned short* __restrict__ A,
                                                  const float* __restrict__ Bf1,
                                                  const float* __restrict__ Bf2,
                                                  float* __restrict__ P,
                                                  int M, int N, int K, int Kper, int ilv) {
    constexpr int FI = TM / 32;          // frags per wave dim; staging copies
    __shared__ unsigned short As[TM * 64];
    __shared__ unsigned short Bs[TM * 64];
    int t = threadIdx.x;
    int lane = t & 63, w = t >> 6;
    int m0 = blockIdx.y * TM, n0 = blockIdx.x * TM;
    int z = blockIdx.z;
    int kbase = z * Kper;
    int wm = (w >> 1) * (TM / 2), wn = (w & 1) * (TM / 2);
    int lr = lane & 15, quad = lane >> 4;
    int rsub = lane >> 3, slot = lane & 7;

    f32x4 acc[FI][FI] = {};

    for (int kk = kbase; kk < kbase + Kper; kk += 64) {
        __syncthreads();
        #pragma unroll
        for (int l = 0; l < FI; ++l) {
            int r = (w * FI + l) * 8 + rsub;
            int c = slot ^ (r & 7);
            ASYNC_COPY16(A + (size_t)(m0 + r) * K + kk + c * 8, As + r * 64 + slot * 8);
            int q8 = kk + c * 8;
            if constexpr (BMODE == 1) {
                const float* src = Bf1 + (size_t)(n0 + r) * 2048 + q8;
                float4 a = *(const float4*)src;
                float4 b = *(const float4*)(src + 4);
                *(uint4*)(Bs + r * 64 + slot * 8) = pack_unit(a, b, 0);
            } else {
                // Hermitian decode of Vi row (n0+r), col group q8..q8+7
                int n = n0 + r;
                int region = q8 >> 11;
                int off = q8 & 2047;
                const float *pa, *pb; int mode;
                if (region == 0) {
                    pa = Bf1 + (size_t)n * MFREQ + off; pb = pa + 4; mode = 0;
                } else if (region == 1) {
                    pa = Bf2 + (size_t)n * MFREQ + off; pb = pa + 4; mode = 1;
                } else {
                    const float* src = (region == 2 ? Bf1 : Bf2) + (size_t)n * MFREQ;
                    if (off < 64) { pa = src; pb = src; mode = 3; }
                    else { pa = src + 4092 - off; pb = src + 4088 - off; mode = 2; }
                }
                float4 a = *(const float4*)pa;
                float4 b = *(const float4*)pb;
                *(uint4*)(Bs + r * 64 + slot * 8) = pack_unit(a, b, mode);
            }
        }
        __syncthreads();
        #pragma unroll
        for (int ks = 0; ks < 2; ++ks) {
            bf16x8 af[FI], bfr[FI];
            #pragma unroll
            for (int i = 0; i < FI; ++i) {
                int row = wm + i * 16 + lr;
                int q = (ks * 4 + quad) ^ (row & 7);
                af[i] = *(const bf16x8*)(As + row * 64 + q * 8);
                int rowb = wn + i * 16 + lr;
                int qb = (ks * 4 + quad) ^ (rowb & 7);
                bfr[i] = *(const bf16x8*)(Bs + rowb * 64 + qb * 8);
            }
            #pragma unroll
            for (int i = 0; i < FI; ++i)
            #pragma unroll
            for (int j = 0; j < FI; ++j)
                acc[i][j] = __builtin_amdgcn_mfma_f32_16x16x32_bf16(af[i], bfr[j], acc[i][j], 0, 0, 0);
        }
    }
    float* Pz = P + (size_t)z * M * N;
    size_t rstride = ilv ? 1024 : (size_t)N;
    #pragma unroll
    for (int i = 0; i < FI; ++i)
    #pragma unroll
    for (int j = 0; j < FI; ++j) {
        int rr = m0 + wm + i * 16 + quad * 4;
        int cc = n0 + wn + j * 16 + lr;
        size_t base = ilv ? ((size_t)(rr & 2047) * 1024 + cc * 2 + (rr >> 11))
                          : ((size_t)rr * N + cc);
        float* cp = Pz + base;
        f32x4 v = acc[i][j];
        cp[0]           = v.x;
        cp[rstride]     = v.y;
        cp[2 * rstride] = v.z;
        cp[3 * rstride] = v.w;
    }
}

// Sum split-K partials: out[i] = alpha * sum_z P[z][i]  (layout-agnostic)
__global__ __launch_bounds__(256) void reduce_k(const float* __restrict__ P,
                                                float* __restrict__ out,
                                                int S, size_t elems, float alpha) {
    size_t idx = ((size_t)blockIdx.x * 256 + threadIdx.x) * 4;
    float4 s = *(const float4*)(P + idx);
    for (int zz = 1; zz < S; ++zz) {
        float4 v = *(const float4*)(P + (size_t)zz * elems + idx);
        s.x += v.x; s.y += v.y; s.z += v.z; s.w += v.w;
    }
    s.x *= alpha; s.y *= alpha; s.z *= alpha; s.w *= alpha;
    *(float4*)(out + idx) = s;
}

// ---------------------------------------------------------------------------
// Middle v5 (unchanged): forward GEMM writes O1 directly; stage O1 rows
// straight to LDS via global_load_lds. g-tile 2, grid 1024 (4 blocks/CU).
__global__ __launch_bounds__(256, 4) void middle_k(const float* __restrict__ O1,
                                                   const unsigned int* __restrict__ wt,
                                                   const float* __restrict__ phi_re,
                                                   const float* __restrict__ phi_im,
                                                   unsigned short* __restrict__ Yt) {
    __shared__ unsigned int sW[2][4096];   // 2 x 16 KB
    __shared__ float sInc[2][1024];        // 2 x 4 KB, interleaved (re,im) per c
    int t = threadIdx.x;
    int g0 = blockIdx.x * 2;
    int b = t >> 5, p = t & 31;

    #pragma unroll
    for (int gt = 0; gt < 2; ++gt) {
        int g = g0 + gt;
        #pragma unroll
        for (int j = 0; j < 4; ++j)
            ASYNC_COPY16(wt + (size_t)g * 4096 + (j * 256 + t) * 4, &sW[gt][(j * 256 + t) * 4]);
        ASYNC_COPY16(O1 + (size_t)g * 1024 + t * 4, &sInc[gt][t * 4]);
    }
    __syncthreads();

    unsigned short reA[2][2], imA[2][2];   // [ch][gt]

    #pragma unroll
    for (int gt = 0; gt < 2; ++gt) {
        int g = g0 + gt;
        float ar0 = 0.f, ai0 = 0.f, ar1 = 0.f, ai1 = 0.f;
        const float2* incp = (const float2*)sInc[gt] + b * 64;
        const unsigned int* wp = sW[gt] + 2 * p;
        #pragma unroll 8
        for (int i = 0; i < 64; ++i) {
            float2 a = incp[i];
            uint2 uu = *(const uint2*)(wp + i * 64);
            float w0r = __uint_as_float(uu.x << 16);
            float w0i = __uint_as_float(uu.x & 0xffff0000u);
            float w1r = __uint_as_float(uu.y << 16);
            float w1i = __uint_as_float(uu.y & 0xffff0000u);
            ar0 += a.x * w0r - a.y * w0i;  ai0 += a.x * w0i + a.y * w0r;
            ar1 += a.x * w1r - a.y * w1i;  ai1 += a.x * w1i + a.y * w1r;
        }
        float pr = phi_re[b * 2048 + g], pi = phi_im[b * 2048 + g];
        reA[0][gt] = f2bf(pr * ar0 - pi * ai0);
        imA[0][gt] = f2bf(pr * ai0 + pi * ar0);
        reA[1][gt] = f2bf(pr * ar1 - pi * ai1);
        imA[1][gt] = f2bf(pr * ai1 + pi * ar1);
    }

    #pragma unroll
    for (int ch = 0; ch < 2; ++ch) {
        int c = 2 * p + ch;
        size_t r0 = (size_t)(b * 64 + c) * 8192;
        size_t rf = (size_t)(b * 64 + 63 - c) * 8192;
        unsigned int ure = (unsigned int)reA[ch][0] | ((unsigned int)reA[ch][1] << 16);
        unsigned int uim = (unsigned int)imA[ch][0] | ((unsigned int)imA[ch][1] << 16);
        *(unsigned int*)(Yt + r0 + g0)        = ure;
        *(unsigned int*)(Yt + r0 + 2048 + g0) = uim;
        *(unsigned int*)(Yt + rf + 4096 + g0) = ure;
        *(unsigned int*)(Yt + rf + 6144 + g0) = uim;
    }
}

// ---------------------------------------------------------------------------
extern "C" void kernel_launch(void* const* d_in, const int* in_sizes, int n_in,
                              void* d_out, int out_size, void* d_ws, size_t ws_size,
                              hipStream_t stream) {
    const float* x     = (const float*)d_in[0];
    const float* emb   = (const float*)d_in[1];
    const float* vf_re = (const float*)d_in[2];
    const float* vf_im = (const float*)d_in[3];
    const float* vi_re = (const float*)d_in[4];
    const float* vi_im = (const float*)d_in[5];
    const float* w1_re = (const float*)d_in[6];
    const float* w1_im = (const float*)d_in[7];
    const float* w2_re = (const float*)d_in[8];
    const float* w2_im = (const float*)d_in[9];
    const float* m1_re = (const float*)d_in[10];
    const float* m1_im = (const float*)d_in[11];
    const float* m2_re = (const float*)d_in[12];
    const float* m2_im = (const float*)d_in[13];

    char* ws = (char*)d_ws;
    unsigned short* Af = (unsigned short*)(ws);                 // 16,777,216
    unsigned int*   Wt = (unsigned int*)(ws + 52428800);        // 33,554,432
    float*          O1 = (float*)(ws + 85983232);               //  8,388,608 (interleaved re,im)
    float*       PhiRe = (float*)(ws + 94371840);               //     65,536
    float*       PhiIm = (float*)(ws + 94437376);               //     65,536
    unsigned short* Yt = (unsigned short*)(ws + 94502912);      //  8,388,608
    float*          P  = (float*)(ws + 102891520);              // 33,554,432 partials
    float* out = (float*)d_out;

    prep_all<<<12288, 256, 0, stream>>>(vf_re, vf_im,
                                        w1_re, w1_im, w2_re, w2_im,
                                        m1_re, m1_im, m2_re, m2_im, emb,
                                        Af, Wt, PhiRe, PhiIm);

    // Forward: O1 (interleaved) = Af[4096x2048] @ x_bf16[512x2048]^T, 64^2
    // tiles, full-K; B staged directly from f32 x (no Xb buffer)
    gemm_sk<64, 1><<<dim3(8, 64, 1), 256, 0, stream>>>(Af, x, nullptr, O1,
                                                       4096, 512, 2048, 2048, 1);

    middle_k<<<1024, 256, 0, stream>>>(O1, Wt, PhiRe, PhiIm, Yt);

    // Inverse: out[512][2048] = (2/N) * Yt[512x8192] @ Herm(Vi)[2048x8192]^T,
    // split-K 8; B staged by on-the-fly Hermitian decode (no Mi buffer)
    gemm_sk<128, 2><<<dim3(16, 4, 8), 256, 0, stream>>>(Yt, vi_re, vi_im, P,
                                                        512, 2048, 8192, 1024, 0);
    reduce_k<<<1024, 256, 0, stream>>>(P, out, 8, (size_t)512 * 2048, 1.0f / 1024.0f);
}

// Round 7
// 314.021 us; speedup vs baseline: 1.1589x; 1.1589x over previous
//
#include <hip/hip_runtime.h>

#define BB    8
#define CC    64
#define NN    2048
#define GG    2048
#define MFREQ 4032

typedef __attribute__((ext_vector_type(4))) float f32x4;
typedef __attribute__((ext_vector_type(8))) short bf16x8;

static __device__ __forceinline__ unsigned short f2bf(float f) {
    union { float f; unsigned u; } v; v.f = f;
    unsigned r = v.u + 0x7fff + ((v.u >> 16) & 1);   // RNE
    return (unsigned short)(r >> 16);
}

static __device__ __forceinline__ unsigned int pk2(float lo, float hi) {
    return (unsigned int)f2bf(lo) | ((unsigned int)f2bf(hi) << 16);
}

static __device__ __forceinline__ uint4 pack_unit(float4 a, float4 b, int mode) {
    uint4 o;
    if (mode == 3) { o.x = o.y = o.z = o.w = 0u; return o; }
    if (mode == 2) {
        o.x = pk2(a.w, a.z); o.y = pk2(a.y, a.x);
        o.z = pk2(b.w, b.z); o.w = pk2(b.y, b.x);
    } else if (mode == 1) {
        o.x = pk2(-a.x, -a.y); o.y = pk2(-a.z, -a.w);
        o.z = pk2(-b.x, -b.y); o.w = pk2(-b.z, -b.w);
    } else {
        o.x = pk2(a.x, a.y); o.y = pk2(a.z, a.w);
        o.z = pk2(b.x, b.y); o.w = pk2(b.z, b.w);
    }
    return o;
}

#define ASYNC_COPY16(gp, lp)                                                        \
    __builtin_amdgcn_global_load_lds(                                               \
        (const __attribute__((address_space(1))) unsigned int*)(gp),                \
        (__attribute__((address_space(3))) unsigned int*)(lp), 16, 0, 0)

// ---------------------------------------------------------------------------
// Streaming unit decode (verified R2-R5): unit = one uint4 store (8 bf16)
// from two float4 loads.
//  units [0, 1048576)        : Af [4096 x 2048]
//  units [1048576, 1179648)  : Xb [512 x 2048]
//  units [1179648, 3276800)  : Mi [2048 x 8192]
// mode: 0 plain, 1 negate, 2 reverse, 3 zero
static __device__ __forceinline__ void decode_unit(int uid,
        const float* __restrict__ vf_re, const float* __restrict__ vf_im,
        const float* __restrict__ x,
        const float* __restrict__ vi_re, const float* __restrict__ vi_im,
        unsigned short* __restrict__ af, unsigned short* __restrict__ xb,
        unsigned short* __restrict__ mi,
        const float*& pa, const float*& pb, unsigned short*& dst, int& mode) {
    if (uid < 1048576) {
        int m = uid >> 8;
        int q8 = (uid & 255) * 8;
        int g = m & 2047;
        int f = (g >> 5) * 63 + (g & 31);
        const float* src = (m < 2048 ? vf_re : vf_im) + (size_t)f * 2048 + q8;
        pa = src; pb = src + 4; dst = af + (size_t)m * 2048 + q8; mode = 0;
    } else if (uid < 1179648) {
        int v = uid - 1048576;
        int q8 = v * 8;
        pa = x + q8; pb = x + q8 + 4; dst = xb + q8; mode = 0;
    } else {
        int v = uid - 1179648;
        int n = v >> 10;
        int q8 = (v & 1023) * 8;
        int region = q8 >> 11;
        int off = q8 & 2047;
        dst = mi + (size_t)n * 8192 + q8;
        if (region == 0) {
            pa = vi_re + (size_t)n * MFREQ + off; pb = pa + 4; mode = 0;
        } else if (region == 1) {
            pa = vi_im + (size_t)n * MFREQ + off; pb = pa + 4; mode = 1;
        } else {
            const float* src = (region == 2 ? vi_re : vi_im) + (size_t)n * MFREQ;
            if (off < 64) { pa = src; pb = src; mode = 3; }
            else { pa = src + 4092 - off; pb = src + 4088 - off; mode = 2; }
        }
    }
}

// ---------------------------------------------------------------------------
// Merged prep v5: NO weight transpose anymore (middle reads w directly).
//  blocks [0, 1280)     : persistent grid-stride streaming (10 units/thread)
//  blocks [1280, 3328)  : phi
__global__ __launch_bounds__(256) void prep_all(const float* __restrict__ vf_re,
                                                const float* __restrict__ vf_im,
                                                const float* __restrict__ x,
                                                const float* __restrict__ vi_re,
                                                const float* __restrict__ vi_im,
                                                const float* __restrict__ m1_re,
                                                const float* __restrict__ m1_im,
                                                const float* __restrict__ m2_re,
                                                const float* __restrict__ m2_im,
                                                const float* __restrict__ emb,
                                                unsigned short* __restrict__ af,
                                                unsigned short* __restrict__ xb,
                                                unsigned short* __restrict__ mi,
                                                float* __restrict__ phi_re,
                                                float* __restrict__ phi_im) {
    __shared__ float sr4[4], si4[4];
    int blk = blockIdx.x;
    int t = threadIdx.x;

    if (blk < 1280) {
        const int STRIDE = 1280 * 256;
        int uid0 = blk * 256 + t;
        const float *pa0, *pb0; unsigned short* d0; int md0;
        decode_unit(uid0, vf_re, vf_im, x, vi_re, vi_im, af, xb, mi, pa0, pb0, d0, md0);
        float4 A0 = *(const float4*)pa0;
        float4 B0 = *(const float4*)pb0;
        #pragma unroll
        for (int i = 1; i <= 10; ++i) {
            const float *pa1 = pa0, *pb1 = pb0; unsigned short* d1 = d0; int md1 = md0;
            float4 A1 = A0, B1 = B0;
            if (i < 10) {
                decode_unit(uid0 + i * STRIDE, vf_re, vf_im, x, vi_re, vi_im,
                            af, xb, mi, pa1, pb1, d1, md1);
                A1 = *(const float4*)pa1;
                B1 = *(const float4*)pb1;
            }
            uint4 o = pack_unit(A0, B0, md0);
            *(uint4*)d0 = o;
            A0 = A1; B0 = B1; d0 = d1; md0 = md1;
            pa0 = pa1; pb0 = pb1;
        }
    } else {
        int g = blk - 1280, e = t;
        int xy = g & 1023;
        const float* mr = (g < 1024 ? m1_re : m2_re) + xy * 256;
        const float* mp = (g < 1024 ? m1_im : m2_im) + xy * 256;
        float vr = mr[e], vi = mp[e];
        for (int bb = 0; bb < 8; ++bb) {
            float em = emb[bb * 256 + e];
            float pr = vr * em, pi = vi * em;
            for (int s = 32; s > 0; s >>= 1) { pr += __shfl_down(pr, s); pi += __shfl_down(pi, s); }
            int wid = e >> 6;
            if ((e & 63) == 0) { sr4[wid] = pr; si4[wid] = pi; }
            __syncthreads();
            if (e == 0) {
                phi_re[bb * 2048 + g] = sr4[0] + sr4[1] + sr4[2] + sr4[3];
                phi_im[bb * 2048 + g] = si4[0] + si4[1] + si4[2] + si4[3];
            }
            __syncthreads();
        }
    }
}

// ---------------------------------------------------------------------------
// Split-K MFMA GEMM, tile TM x TM, serial R3 schedule (proven).
// ilv=1 (forward): O1 layout [cc][g][ri]: element (rr,cc) at
//   cc*4096 + (rr&2047)*2 + (rr>>11), row-stride 2 (consecutive g).
template<int TM>
__global__ __launch_bounds__(256, 2) void gemm_sk(const unsigned short* __restrict__ A,
                                                  const unsigned short* __restrict__ Bm,
                                                  float* __restrict__ P,
                                                  int M, int N, int K, int Kper, int ilv) {
    constexpr int FI = TM / 32;          // frags per wave dim; staging copies
    __shared__ unsigned short As[TM * 64];
    __shared__ unsigned short Bs[TM * 64];
    int t = threadIdx.x;
    int lane = t & 63, w = t >> 6;
    int m0 = blockIdx.y * TM, n0 = blockIdx.x * TM;
    int z = blockIdx.z;
    int kbase = z * Kper;
    int wm = (w >> 1) * (TM / 2), wn = (w & 1) * (TM / 2);
    int lr = lane & 15, quad = lane >> 4;
    int rsub = lane >> 3, slot = lane & 7;

    f32x4 acc[FI][FI] = {};

    for (int kk = kbase; kk < kbase + Kper; kk += 64) {
        __syncthreads();
        #pragma unroll
        for (int l = 0; l < FI; ++l) {
            int r = (w * FI + l) * 8 + rsub;
            int c = slot ^ (r & 7);
            ASYNC_COPY16(A + (size_t)(m0 + r) * K + kk + c * 8, As + r * 64 + slot * 8);
            ASYNC_COPY16(Bm + (size_t)(n0 + r) * K + kk + c * 8, Bs + r * 64 + slot * 8);
        }
        __syncthreads();
        #pragma unroll
        for (int ks = 0; ks < 2; ++ks) {
            bf16x8 af[FI], bfr[FI];
            #pragma unroll
            for (int i = 0; i < FI; ++i) {
                int row = wm + i * 16 + lr;
                int q = (ks * 4 + quad) ^ (row & 7);
                af[i] = *(const bf16x8*)(As + row * 64 + q * 8);
                int rowb = wn + i * 16 + lr;
                int qb = (ks * 4 + quad) ^ (rowb & 7);
                bfr[i] = *(const bf16x8*)(Bs + rowb * 64 + qb * 8);
            }
            #pragma unroll
            for (int i = 0; i < FI; ++i)
            #pragma unroll
            for (int j = 0; j < FI; ++j)
                acc[i][j] = __builtin_amdgcn_mfma_f32_16x16x32_bf16(af[i], bfr[j], acc[i][j], 0, 0, 0);
        }
    }
    float* Pz = P + (size_t)z * M * N;
    size_t rstride = ilv ? 2 : (size_t)N;
    #pragma unroll
    for (int i = 0; i < FI; ++i)
    #pragma unroll
    for (int j = 0; j < FI; ++j) {
        int rr = m0 + wm + i * 16 + quad * 4;
        int cc = n0 + wn + j * 16 + lr;
        size_t base = ilv ? ((size_t)cc * 4096 + (size_t)(rr & 2047) * 2 + (rr >> 11))
                          : ((size_t)rr * N + cc);
        float* cp = Pz + base;
        f32x4 v = acc[i][j];
        cp[0]           = v.x;
        cp[rstride]     = v.y;
        cp[2 * rstride] = v.z;
        cp[3 * rstride] = v.w;
    }
}

// Sum split-K partials: out[i] = alpha * sum_z P[z][i]  (layout-agnostic)
__global__ __launch_bounds__(256) void reduce_k(const float* __restrict__ P,
                                                float* __restrict__ out,
                                                int S, size_t elems, float alpha) {
    size_t idx = ((size_t)blockIdx.x * 256 + threadIdx.x) * 4;
    float4 s = *(const float4*)(P + idx);
    for (int zz = 1; zz < S; ++zz) {
        float4 v = *(const float4*)(P + (size_t)zz * elems + idx);
        s.x += v.x; s.y += v.y; s.z += v.z; s.w += v.w;
    }
    s.x *= alpha; s.y *= alpha; s.z *= alpha; s.w *= alpha;
    *(float4*)(out + idx) = s;
}

// ---------------------------------------------------------------------------
// Middle v6: reads w1/w2 f32 DIRECTLY (no Wt transpose, no Wt buffer).
// Block = (g-tile 32) x (o-half 32) x (b-pair); loop i=0..63.
// W read w[(i*64+o)*1024 + xy + gq*4] = coalesced float4 of ORIGINAL layout.
// O1 is [bc][g][ri] (fwd ilv writes it that way); block's 128 bc-rows x 32 g
// slice (32 KB) staged via global_load_lds.
__global__ __launch_bounds__(256) void middle_k2(const float* __restrict__ O1,
                                                 const float* __restrict__ w1_re,
                                                 const float* __restrict__ w1_im,
                                                 const float* __restrict__ w2_re,
                                                 const float* __restrict__ w2_im,
                                                 const float* __restrict__ phi_re,
                                                 const float* __restrict__ phi_im,
                                                 unsigned short* __restrict__ Yt) {
    __shared__ float sO1[128 * 64];     // [row=b*64+i][32g x {re,im}] = 32 KB
    int t = threadIdx.x;
    int bx = blockIdx.x;                // 512 = 64 gt x 2 os x 4 bp
    int g0 = (bx & 63) * 32;
    int o0 = ((bx >> 6) & 1) * 32;
    int b0 = (bx >> 7) * 2;
    const float* wre = (g0 < 1024 ? w1_re : w2_re);
    const float* wim = (g0 < 1024 ? w1_im : w2_im);
    int xyb = g0 & 1023;

    // stage O1 rows [b0*64, b0*64+128) x floats [g0*2, g0*2+64)
    #pragma unroll
    for (int s = 0; s < 8; ++s) {
        int idx = s * 256 + t;          // 2048 x 16B = 32 KB
        int row = idx >> 4;
        int off = (idx & 15) * 4;
        ASYNC_COPY16(O1 + (size_t)(b0 * 64 + row) * 4096 + g0 * 2 + off,
                     sO1 + row * 64 + off);
    }
    __syncthreads();

    int ol = t >> 3, gq = t & 7;        // 32 o-lanes x 8 g-quads
    int o = o0 + ol;
    float accr[2][4] = {}, acci[2][4] = {};

    #pragma unroll 4
    for (int i = 0; i < 64; ++i) {
        size_t wrow = (size_t)(i * 64 + o) * 1024 + xyb + gq * 4;
        float4 wr = *(const float4*)(wre + wrow);
        float4 wi = *(const float4*)(wim + wrow);
        #pragma unroll
        for (int b = 0; b < 2; ++b) {
            const float* op = sO1 + (b * 64 + i) * 64 + gq * 8;
            float4 oa = *(const float4*)op;        // re0 im0 re1 im1
            float4 ob = *(const float4*)(op + 4);  // re2 im2 re3 im3
            accr[b][0] += wr.x * oa.x - wi.x * oa.y;
            acci[b][0] += wr.x * oa.y + wi.x * oa.x;
            accr[b][1] += wr.y * oa.z - wi.y * oa.w;
            acci[b][1] += wr.y * oa.w + wi.y * oa.z;
            accr[b][2] += wr.z * ob.x - wi.z * ob.y;
            acci[b][2] += wr.z * ob.y + wi.z * ob.x;
            accr[b][3] += wr.w * ob.z - wi.w * ob.w;
            acci[b][3] += wr.w * ob.w + wi.w * ob.z;
        }
    }

    int g4 = g0 + gq * 4;
    #pragma unroll
    for (int b = 0; b < 2; ++b) {
        int bb = b0 + b;
        float4 pr = *(const float4*)(phi_re + bb * 2048 + g4);
        float4 pi = *(const float4*)(phi_im + bb * 2048 + g4);
        ushort4 vre, vim;
        vre.x = f2bf(pr.x * accr[b][0] - pi.x * acci[b][0]);
        vim.x = f2bf(pr.x * acci[b][0] + pi.x * accr[b][0]);
        vre.y = f2bf(pr.y * accr[b][1] - pi.y * acci[b][1]);
        vim.y = f2bf(pr.y * acci[b][1] + pi.y * accr[b][1]);
        vre.z = f2bf(pr.z * accr[b][2] - pi.z * acci[b][2]);
        vim.z = f2bf(pr.z * acci[b][2] + pi.z * accr[b][2]);
        vre.w = f2bf(pr.w * accr[b][3] - pi.w * acci[b][3]);
        vim.w = f2bf(pr.w * acci[b][3] + pi.w * accr[b][3]);
        size_t r0 = (size_t)(bb * 64 + o) * 8192;
        size_t rf = (size_t)(bb * 64 + 63 - o) * 8192;
        *(ushort4*)(Yt + r0 + g4)        = vre;
        *(ushort4*)(Yt + r0 + 2048 + g4) = vim;
        *(ushort4*)(Yt + rf + 4096 + g4) = vre;
        *(ushort4*)(Yt + rf + 6144 + g4) = vim;
    }
}

// ---------------------------------------------------------------------------
extern "C" void kernel_launch(void* const* d_in, const int* in_sizes, int n_in,
                              void* d_out, int out_size, void* d_ws, size_t ws_size,
                              hipStream_t stream) {
    const float* x     = (const float*)d_in[0];
    const float* emb   = (const float*)d_in[1];
    const float* vf_re = (const float*)d_in[2];
    const float* vf_im = (const float*)d_in[3];
    const float* vi_re = (const float*)d_in[4];
    const float* vi_im = (const float*)d_in[5];
    const float* w1_re = (const float*)d_in[6];
    const float* w1_im = (const float*)d_in[7];
    const float* w2_re = (const float*)d_in[8];
    const float* w2_im = (const float*)d_in[9];
    const float* m1_re = (const float*)d_in[10];
    const float* m1_im = (const float*)d_in[11];
    const float* m2_re = (const float*)d_in[12];
    const float* m2_im = (const float*)d_in[13];

    char* ws = (char*)d_ws;
    unsigned short* Af = (unsigned short*)(ws);                 // 16,777,216
    unsigned short* Xb = (unsigned short*)(ws + 16777216);      //  2,097,152
    unsigned short* Mi = (unsigned short*)(ws + 18874368);      // 33,554,432
    float*          O1 = (float*)(ws + 85983232);               //  8,388,608 ([bc][g][ri])
    float*       PhiRe = (float*)(ws + 94371840);               //     65,536
    float*       PhiIm = (float*)(ws + 94437376);               //     65,536
    unsigned short* Yt = (unsigned short*)(ws + 94502912);      //  8,388,608
    float*          P  = (float*)(ws + 102891520);              // 33,554,432 partials
    float* out = (float*)d_out;

    prep_all<<<3328, 256, 0, stream>>>(vf_re, vf_im, x, vi_re, vi_im,
                                       m1_re, m1_im, m2_re, m2_im, emb,
                                       Af, Xb, Mi, PhiRe, PhiIm);

    // Forward: O1[bc][g][ri] = Af[4096x2048] @ Xb[512x2048]^T, 64^2 tiles,
    // full-K (no split-K, no reduce)
    gemm_sk<64><<<dim3(8, 64, 1), 256, 0, stream>>>(Af, Xb, O1, 4096, 512, 2048, 2048, 1);

    middle_k2<<<512, 256, 0, stream>>>(O1, w1_re, w1_im, w2_re, w2_im,
                                       PhiRe, PhiIm, Yt);

    // Inverse: out[512][2048] = (2/N) * Yt[512x8192] @ Mi[2048x8192]^T, split-K 8
    gemm_sk<128><<<dim3(16, 4, 8), 256, 0, stream>>>(Yt, Mi, P, 512, 2048, 8192, 1024, 0);
    reduce_k<<<1024, 256, 0, stream>>>(P, out, 8, (size_t)512 * 2048, 1.0f / 1024.0f);
}